// Round 3
// baseline (661.096 us; speedup 1.0000x reference)
//
#include <hip/hip_runtime.h>

#define N_NODES 100000
#define N_EDGES 1200000
#define D 64
#define KEEP_PROB 0.7f
#define INV_KEEP (1.0f / KEEP_PROB)

// ---------------------------------------------------------------------------
__global__ __launch_bounds__(256) void zero_kernel(float4* __restrict__ p, int n4) {
    int i = blockIdx.x * 256 + threadIdx.x;
    if (i < n4) p[i] = make_float4(0.f, 0.f, 0.f, 0.f);
}

// ---------------------------------------------------------------------------
// CSR build 1: per-row counts (into `cnt`, later reused as scatter cursor)
__global__ __launch_bounds__(256) void hist_kernel(const int* __restrict__ rows,
                                                   int* __restrict__ cnt) {
    int e = blockIdx.x * 256 + threadIdx.x;
    if (e < N_EDGES) atomicAdd(&cnt[rows[e]], 1);
}

// ---------------------------------------------------------------------------
// CSR build 2: single 256-thread block. Exclusive scan of cnt ->
//   Pstart[0..N_NODES] (with sentinel), and cursor[j] = start (overwrites cnt).
__global__ __launch_bounds__(256) void scan_kernel(int* __restrict__ cnt_cursor,
                                                   int* __restrict__ Pstart) {
    __shared__ int part[256];
    const int CHUNK = 391;  // 256*391 = 100096 >= N_NODES
    int t = threadIdx.x;
    int base = t * CHUNK;
    int s = 0;
    for (int i = 0; i < CHUNK; ++i) {
        int j = base + i;
        if (j < N_NODES) s += cnt_cursor[j];
    }
    part[t] = s;
    __syncthreads();
    // Hillis-Steele inclusive scan over 256 partials (double-barrier)
    for (int d = 1; d < 256; d <<= 1) {
        int v = (t >= d) ? part[t - d] : 0;
        __syncthreads();
        part[t] += v;
        __syncthreads();
    }
    int run = part[t] - s;  // exclusive prefix of this thread's chunk
    for (int i = 0; i < CHUNK; ++i) {
        int j = base + i;
        if (j < N_NODES) {
            int cj = cnt_cursor[j];
            Pstart[j] = run;
            cnt_cursor[j] = run;   // cursor init
            run += cj;
        }
    }
    if (t == 255) Pstart[N_NODES] = run;  // == N_EDGES
}

// ---------------------------------------------------------------------------
// CSR build 3: scatter edges into row-grouped order via atomic cursor.
// cursor is atomically bumped and NEVER read by any later kernel.
__global__ __launch_bounds__(256) void scatter_kernel(
    const int*   __restrict__ rows,
    const int*   __restrict__ cols,
    const float* __restrict__ vals,
    const float* __restrict__ drop_u,   // [2, E]
    int*         __restrict__ cursor,
    int*         __restrict__ scols,
    float*       __restrict__ sv0,
    float*       __restrict__ sv1) {
    int e = blockIdx.x * 256 + threadIdx.x;
    if (e >= N_EDGES) return;
    int r = rows[e];
    int pos = atomicAdd(&cursor[r], 1);
    scols[pos] = cols[e];
    float v = vals[e] * INV_KEEP;
    sv0[pos] = (drop_u[e] + KEEP_PROB >= 1.0f) ? v : 0.f;
    sv1[pos] = (drop_u[N_EDGES + e] + KEEP_PROB >= 1.0f) ? v : 0.f;
}

// ---------------------------------------------------------------------------
// Gather SpMM: one wave per row, one lane per feature. No atomics, branch-free.
// mode 0: io[row] = acc
// mode 1: io[row] = (io[row] + acc) / 3
__global__ __launch_bounds__(256) void spmm_gather_kernel(
    const float* __restrict__ x_in,
    const int*   __restrict__ scols,
    const float* __restrict__ sv,
    const int*   __restrict__ Pstart,
    float*       __restrict__ io,
    int mode) {
    int wave = (blockIdx.x * 256 + threadIdx.x) >> 6;
    int lane = threadIdx.x & 63;
    if (wave >= N_NODES) return;
    // coherence-point loads (belt-and-braces vs stale per-XCD L2 copies)
    int start = __hip_atomic_load(&Pstart[wave],     __ATOMIC_RELAXED, __HIP_MEMORY_SCOPE_AGENT);
    int end   = __hip_atomic_load(&Pstart[wave + 1], __ATOMIC_RELAXED, __HIP_MEMORY_SCOPE_AGENT);
    float acc = 0.f;
    #pragma unroll 4
    for (int i = start; i < end; ++i) {
        int   c = scols[i];
        float v = sv[i];                       // 0 for dropped edges
        acc = fmaf(v, x_in[(c << 6) + lane], acc);
    }
    int o = (wave << 6) + lane;
    if (mode == 0) io[o] = acc;
    else           io[o] = (io[o] + acc) * (1.0f / 3.0f);
}

// ---------------------------------------------------------------------------
// out[n,j] = b[j] + sum_k emb[n,k]*W[j,k] + x1[n,j]
__global__ __launch_bounds__(256) void fc_add_kernel(
    const float* __restrict__ emb,
    const float* __restrict__ W,
    const float* __restrict__ b,
    const float* __restrict__ x1,
    float*       __restrict__ out) {
    __shared__ float Ws[D * 65];
    __shared__ float Es[4 * D];

    int t = threadIdx.x;
    #pragma unroll
    for (int i = 0; i < 16; ++i) {
        int idx = i * 256 + t;
        Ws[(idx >> 6) * 65 + (idx & 63)] = W[idx];
    }
    int node0 = blockIdx.x * 4;
    Es[t] = emb[node0 * D + t];
    __syncthreads();

    int local = t >> 6;
    int j     = t & 63;
    int n     = node0 + local;

    float acc = b[j];
    const float* es = &Es[local * D];
    const float* ws = &Ws[j * 65];
    #pragma unroll
    for (int k = 0; k < D; ++k) acc += es[k] * ws[k];
    out[n * D + j] = acc + x1[n * D + j];
}

// ---------------------------------------------------------------------------
// Fallback (R1 atomic path, replay-proven) if ws too small
__global__ __launch_bounds__(256) void spmm_atomic_kernel(
    const float* __restrict__ x_in,
    const float* __restrict__ vals,
    const float* __restrict__ drop_u,
    const int*   __restrict__ rows,
    const int*   __restrict__ cols,
    float*       __restrict__ x_out) {
    int wave = (blockIdx.x * 256 + threadIdx.x) >> 6;
    int lane = threadIdx.x & 63;
    if (wave >= N_EDGES) return;
    float u = drop_u[wave];
    if (u + KEEP_PROB < 1.0f) return;
    float v = vals[wave] * INV_KEEP;
    atomicAdd(&x_out[rows[wave] * D + lane], v * x_in[cols[wave] * D + lane]);
}

__global__ __launch_bounds__(256) void scale_kernel(float4* __restrict__ p, int n4) {
    int i = blockIdx.x * 256 + threadIdx.x;
    if (i < n4) {
        float4 v = p[i];
        v.x *= (1.f/3.f); v.y *= (1.f/3.f); v.z *= (1.f/3.f); v.w *= (1.f/3.f);
        p[i] = v;
    }
}

// ---------------------------------------------------------------------------
extern "C" void kernel_launch(void* const* d_in, const int* in_sizes, int n_in,
                              void* d_out, int out_size, void* d_ws, size_t ws_size,
                              hipStream_t stream) {
    const float* all_emb = (const float*)d_in[0];
    const float* W       = (const float*)d_in[1];
    const float* b       = (const float*)d_in[2];
    const float* vals    = (const float*)d_in[3];
    const float* drop_u  = (const float*)d_in[4];   // [2, E]
    const int*   rows    = (const int*)d_in[5];
    const int*   cols    = (const int*)d_in[6];

    float* out = (float*)d_out;

    // workspace layout (16B aligned)
    char* ws = (char*)d_ws;
    float* x1     = (float*)(ws);                   // 25,600,000 B
    int*   Pstart = (int*)  (ws + 25600000);        //    400,064 B (N+1 ints, padded)
    int*   cursor = (int*)  (ws + 26000064);        //    400,000 B (counts, then cursor)
    int*   scols  = (int*)  (ws + 26400064);        //  4,800,000 B
    float* sv0    = (float*)(ws + 31200064);        //  4,800,000 B
    float* sv1    = (float*)(ws + 36000064);        //  4,800,000 B
    const size_t WS_NEEDED = 40800064;

    const int n4 = N_NODES * D / 4;
    const int zb = (n4 + 255) / 256;
    const int edge_blocks = (N_EDGES + 255) / 256;     // 4688
    const int row_wave_blocks = (N_NODES + 3) / 4;     // 25000

    if (ws_size >= WS_NEEDED) {
        // CSR build (identical rows/cols both layers; dropout pre-folded)
        zero_kernel<<<(N_NODES/4 + 255)/256, 256, 0, stream>>>((float4*)cursor, N_NODES/4);
        hist_kernel<<<edge_blocks, 256, 0, stream>>>(rows, cursor);
        scan_kernel<<<1, 256, 0, stream>>>(cursor, Pstart);
        scatter_kernel<<<edge_blocks, 256, 0, stream>>>(rows, cols, vals, drop_u,
                                                        cursor, scols, sv0, sv1);
        // layer 0: x1 = A1 @ all_emb
        spmm_gather_kernel<<<row_wave_blocks, 256, 0, stream>>>(
            all_emb, scols, sv0, Pstart, x1, 0);
        // out = fc(all_emb) + x1
        fc_add_kernel<<<N_NODES / 4, 256, 0, stream>>>(all_emb, W, b, x1, out);
        // layer 1 (fused /3): out = (out + A2 @ x1) / 3
        spmm_gather_kernel<<<row_wave_blocks, 256, 0, stream>>>(
            x1, scols, sv1, Pstart, out, 1);
    } else {
        // fallback: proven atomic path
        const int spmm_blocks = (N_EDGES + 3) / 4;
        zero_kernel<<<zb, 256, 0, stream>>>((float4*)x1, n4);
        spmm_atomic_kernel<<<spmm_blocks, 256, 0, stream>>>(all_emb, vals, drop_u,
                                                            rows, cols, x1);
        fc_add_kernel<<<N_NODES / 4, 256, 0, stream>>>(all_emb, W, b, x1, out);
        spmm_atomic_kernel<<<spmm_blocks, 256, 0, stream>>>(x1, vals,
                                                            drop_u + N_EDGES,
                                                            rows, cols, out);
        scale_kernel<<<zb, 256, 0, stream>>>((float4*)out, n4);
    }
}

// Round 4
// 445.363 us; speedup vs baseline: 1.4844x; 1.4844x over previous
//
#include <hip/hip_runtime.h>

#define N_NODES 100000
#define N_EDGES 1200000
#define D 64
#define KEEP_PROB 0.7f
#define INV_KEEP (1.0f / KEEP_PROB)
#define NB_SCAN 196   // ceil(N_NODES/512); 196*512 = 100352

#define ALOAD_I(p) __hip_atomic_load((p), __ATOMIC_RELAXED, __HIP_MEMORY_SCOPE_AGENT)
#define ALOAD_F(p) __hip_atomic_load((p), __ATOMIC_RELAXED, __HIP_MEMORY_SCOPE_AGENT)

// ---------------------------------------------------------------------------
__global__ __launch_bounds__(256) void zero_kernel(float4* __restrict__ p, int n4) {
    int i = blockIdx.x * 256 + threadIdx.x;
    if (i < n4) p[i] = make_float4(0.f, 0.f, 0.f, 0.f);
}

// ---------------------------------------------------------------------------
// CSR build 1: per-row counts
__global__ __launch_bounds__(256) void hist_kernel(const int* __restrict__ rows,
                                                   int* __restrict__ cnt) {
    int e = blockIdx.x * 256 + threadIdx.x;
    if (e < N_EDGES) atomicAdd(&cnt[rows[e]], 1);
}

// ---------------------------------------------------------------------------
// CSR build 2a: per-block (512-elem chunk) sums of cnt.
// cnt's latest values came from memory-side atomic RMW -> agent-scope loads.
__global__ __launch_bounds__(256) void blocksum_kernel(const int* __restrict__ cnt,
                                                       int* __restrict__ bsum) {
    __shared__ int red[256];
    int t = threadIdx.x;
    int base = blockIdx.x * 512;
    int i0 = base + t, i1 = base + 256 + t;
    int s = 0;
    if (i0 < N_NODES) s += ALOAD_I(&cnt[i0]);
    if (i1 < N_NODES) s += ALOAD_I(&cnt[i1]);
    red[t] = s;
    __syncthreads();
    for (int d = 128; d > 0; d >>= 1) {
        if (t < d) red[t] += red[t + d];
        __syncthreads();
    }
    if (t == 0) bsum[blockIdx.x] = red[0];
}

// ---------------------------------------------------------------------------
// CSR build 2b: exclusive scan of the 196 block sums (in place); sentinel.
__global__ __launch_bounds__(256) void bscan_kernel(int* __restrict__ bsum,
                                                    int* __restrict__ Pstart) {
    __shared__ int part[256];
    int t = threadIdx.x;
    int v = (t < NB_SCAN) ? bsum[t] : 0;
    part[t] = v;
    __syncthreads();
    for (int d = 1; d < 256; d <<= 1) {
        int w = (t >= d) ? part[t - d] : 0;
        __syncthreads();
        part[t] += w;
        __syncthreads();
    }
    if (t < NB_SCAN) bsum[t] = part[t] - v;   // exclusive block offset
    if (t == 0) Pstart[N_NODES] = N_EDGES;
}

// ---------------------------------------------------------------------------
// CSR build 2c: block-local exclusive scan + block offset -> Pstart, cursor.
__global__ __launch_bounds__(256) void scan2_kernel(const int* __restrict__ cnt,
                                                    const int* __restrict__ bofs,
                                                    int* __restrict__ Pstart,
                                                    int* __restrict__ cursor) {
    __shared__ int part[256];
    int t = threadIdx.x;
    int base = blockIdx.x * 512;
    int i0 = base + 2 * t, i1 = i0 + 1;
    int e0 = (i0 < N_NODES) ? ALOAD_I(&cnt[i0]) : 0;
    int e1 = (i1 < N_NODES) ? ALOAD_I(&cnt[i1]) : 0;
    int s = e0 + e1;
    part[t] = s;
    __syncthreads();
    for (int d = 1; d < 256; d <<= 1) {
        int w = (t >= d) ? part[t - d] : 0;
        __syncthreads();
        part[t] += w;
        __syncthreads();
    }
    int pref = bofs[blockIdx.x] + part[t] - s;   // exclusive prefix of i0
    if (i0 < N_NODES) { Pstart[i0] = pref;      cursor[i0] = pref; }
    if (i1 < N_NODES) { Pstart[i1] = pref + e0; cursor[i1] = pref + e0; }
}

// ---------------------------------------------------------------------------
// CSR build 3: scatter edges row-grouped via atomic cursor (cursor never read
// again). Dropout pre-folded into per-layer weights.
__global__ __launch_bounds__(256) void scatter_kernel(
    const int*   __restrict__ rows,
    const int*   __restrict__ cols,
    const float* __restrict__ vals,
    const float* __restrict__ drop_u,   // [2, E]
    int*         __restrict__ cursor,
    int*         __restrict__ scols,
    float*       __restrict__ sv0,
    float*       __restrict__ sv1) {
    int e = blockIdx.x * 256 + threadIdx.x;
    if (e >= N_EDGES) return;
    int r = rows[e];
    int pos = atomicAdd(&cursor[r], 1);
    scols[pos] = cols[e];
    float v = vals[e] * INV_KEEP;
    sv0[pos] = (drop_u[e] + KEEP_PROB >= 1.0f) ? v : 0.f;
    sv1[pos] = (drop_u[N_EDGES + e] + KEEP_PROB >= 1.0f) ? v : 0.f;
}

// ---------------------------------------------------------------------------
// Gather SpMM: one wave per row, one lane per feature, branch-free.
// scols/sv content is replay-nondeterministic (scatter permutation) -> stale
// per-XCD L2 lines from a previous replay are a real hazard: agent-scope loads.
// mode 0: io[row] = acc ; mode 1: io[row] = (io[row] + acc) / 3
__global__ __launch_bounds__(256) void spmm_gather_kernel(
    const float* __restrict__ x_in,
    const int*   __restrict__ scols,
    const float* __restrict__ sv,
    const int*   __restrict__ Pstart,
    float*       __restrict__ io,
    int mode) {
    int wave = (blockIdx.x * 256 + threadIdx.x) >> 6;
    int lane = threadIdx.x & 63;
    if (wave >= N_NODES) return;
    int start = Pstart[wave];
    int end   = Pstart[wave + 1];
    float acc = 0.f;
    #pragma unroll 4
    for (int i = start; i < end; ++i) {
        int   c = ALOAD_I(&scols[i]);
        float v = ALOAD_F(&sv[i]);             // 0 for dropped edges
        acc = fmaf(v, x_in[(c << 6) + lane], acc);
    }
    int o = (wave << 6) + lane;
    if (mode == 0) io[o] = acc;
    else           io[o] = (io[o] + acc) * (1.0f / 3.0f);
}

// ---------------------------------------------------------------------------
// out[n,j] = b[j] + sum_k emb[n,k]*W[j,k] + x1[n,j]
__global__ __launch_bounds__(256) void fc_add_kernel(
    const float* __restrict__ emb,
    const float* __restrict__ W,
    const float* __restrict__ b,
    const float* __restrict__ x1,
    float*       __restrict__ out) {
    __shared__ float Ws[D * 65];
    __shared__ float Es[4 * D];

    int t = threadIdx.x;
    #pragma unroll
    for (int i = 0; i < 16; ++i) {
        int idx = i * 256 + t;
        Ws[(idx >> 6) * 65 + (idx & 63)] = W[idx];
    }
    int node0 = blockIdx.x * 4;
    Es[t] = emb[node0 * D + t];
    __syncthreads();

    int local = t >> 6;
    int j     = t & 63;
    int n     = node0 + local;

    float acc = b[j];
    const float* es = &Es[local * D];
    const float* ws = &Ws[j * 65];
    #pragma unroll
    for (int k = 0; k < D; ++k) acc += es[k] * ws[k];
    out[n * D + j] = acc + x1[n * D + j];
}

// ---------------------------------------------------------------------------
// Fallback (R1 atomic path, replay-proven) if ws too small
__global__ __launch_bounds__(256) void spmm_atomic_kernel(
    const float* __restrict__ x_in,
    const float* __restrict__ vals,
    const float* __restrict__ drop_u,
    const int*   __restrict__ rows,
    const int*   __restrict__ cols,
    float*       __restrict__ x_out) {
    int wave = (blockIdx.x * 256 + threadIdx.x) >> 6;
    int lane = threadIdx.x & 63;
    if (wave >= N_EDGES) return;
    float u = drop_u[wave];
    if (u + KEEP_PROB < 1.0f) return;
    float v = vals[wave] * INV_KEEP;
    atomicAdd(&x_out[rows[wave] * D + lane], v * x_in[cols[wave] * D + lane]);
}

__global__ __launch_bounds__(256) void scale_kernel(float4* __restrict__ p, int n4) {
    int i = blockIdx.x * 256 + threadIdx.x;
    if (i < n4) {
        float4 v = p[i];
        v.x *= (1.f/3.f); v.y *= (1.f/3.f); v.z *= (1.f/3.f); v.w *= (1.f/3.f);
        p[i] = v;
    }
}

// ---------------------------------------------------------------------------
extern "C" void kernel_launch(void* const* d_in, const int* in_sizes, int n_in,
                              void* d_out, int out_size, void* d_ws, size_t ws_size,
                              hipStream_t stream) {
    const float* all_emb = (const float*)d_in[0];
    const float* W       = (const float*)d_in[1];
    const float* b       = (const float*)d_in[2];
    const float* vals    = (const float*)d_in[3];
    const float* drop_u  = (const float*)d_in[4];   // [2, E]
    const int*   rows    = (const int*)d_in[5];
    const int*   cols    = (const int*)d_in[6];

    float* out = (float*)d_out;

    // workspace layout (16B aligned)
    char* ws = (char*)d_ws;
    float* x1     = (float*)(ws);                   // 25,600,000 B
    int*   Pstart = (int*)  (ws + 25600000);        //    400,064 B (N+1 ints, padded)
    int*   cnt    = (int*)  (ws + 26000064);        //    400,000 B (counts -> cursor)
    int*   scols  = (int*)  (ws + 26400064);        //  4,800,000 B
    float* sv0    = (float*)(ws + 31200064);        //  4,800,000 B
    float* sv1    = (float*)(ws + 36000064);        //  4,800,000 B
    int*   bsum   = (int*)  (ws + 40800064);        //      1,024 B (196 ints)
    const size_t WS_NEEDED = 40801088;

    const int n4 = N_NODES * D / 4;
    const int zb = (n4 + 255) / 256;
    const int edge_blocks = (N_EDGES + 255) / 256;     // 4688
    const int row_wave_blocks = (N_NODES + 3) / 4;     // 25000

    if (ws_size >= WS_NEEDED) {
        // CSR build (rows/cols shared by both layers; dropout pre-folded)
        zero_kernel<<<(N_NODES/4 + 255)/256, 256, 0, stream>>>((float4*)cnt, N_NODES/4);
        hist_kernel<<<edge_blocks, 256, 0, stream>>>(rows, cnt);
        blocksum_kernel<<<NB_SCAN, 256, 0, stream>>>(cnt, bsum);
        bscan_kernel<<<1, 256, 0, stream>>>(bsum, Pstart);
        scan2_kernel<<<NB_SCAN, 256, 0, stream>>>(cnt, bsum, Pstart, cnt);
        scatter_kernel<<<edge_blocks, 256, 0, stream>>>(rows, cols, vals, drop_u,
                                                        cnt, scols, sv0, sv1);
        // layer 0: x1 = A1 @ all_emb
        spmm_gather_kernel<<<row_wave_blocks, 256, 0, stream>>>(
            all_emb, scols, sv0, Pstart, x1, 0);
        // out = fc(all_emb) + x1
        fc_add_kernel<<<N_NODES / 4, 256, 0, stream>>>(all_emb, W, b, x1, out);
        // layer 1 (fused /3): out = (out + A2 @ x1) / 3
        spmm_gather_kernel<<<row_wave_blocks, 256, 0, stream>>>(
            x1, scols, sv1, Pstart, out, 1);
    } else {
        // fallback: proven atomic path
        const int spmm_blocks = (N_EDGES + 3) / 4;
        zero_kernel<<<zb, 256, 0, stream>>>((float4*)x1, n4);
        spmm_atomic_kernel<<<spmm_blocks, 256, 0, stream>>>(all_emb, vals, drop_u,
                                                            rows, cols, x1);
        fc_add_kernel<<<N_NODES / 4, 256, 0, stream>>>(all_emb, W, b, x1, out);
        spmm_atomic_kernel<<<spmm_blocks, 256, 0, stream>>>(x1, vals,
                                                            drop_u + N_EDGES,
                                                            rows, cols, out);
        scale_kernel<<<zb, 256, 0, stream>>>((float4*)out, n4);
    }
}